// Round 6
// baseline (304.042 us; speedup 1.0000x reference)
//
#include <hip/hip_runtime.h>

typedef unsigned short u16;
typedef unsigned int   u32;
typedef __bf16 bf16x8 __attribute__((ext_vector_type(8)));
typedef float  f32x4  __attribute__((ext_vector_type(4)));

// Contract (established R0-R5): inputs f32 (in_npz 31MB = 8M elems x 4B;
// bf16 interp -> NaN). Outputs f32 (bit-identical 3.706 = max|k_lat| across
// 3 arithmetic variants = our u16 writes re-read as f32; ref y max 0.245).

__device__ __forceinline__ float b2f(u16 u) {
    u32 x = ((u32)u) << 16; float f; __builtin_memcpy(&f, &x, 4); return f;
}
__device__ __forceinline__ u16 f2b(float f) {
    u32 x; __builtin_memcpy(&x, &f, 4);
    u32 r = x + 0x7FFFu + ((x >> 16) & 1u);
    return (u16)(r >> 16);
}

// ---------------------------------------------------------------------------
// x f32 [4096][1024] -> bf16 copy (lives in d_out y-region scratch)
// ---------------------------------------------------------------------------
__global__ __launch_bounds__(256) void convert_x(
    const float* __restrict__ x, u16* __restrict__ xb)
{
    int i0 = (blockIdx.x * 256 + threadIdx.x) * 8;
    #pragma unroll
    for (int j = 0; j < 8; j++) xb[i0 + j] = f2b(x[i0 + j]);
}

// ---------------------------------------------------------------------------
// Transpose 4 f32 [1024][1024] weights into bf16 WT[n][k] = W[k][n]
// ---------------------------------------------------------------------------
__global__ __launch_bounds__(256) void transpose4(
    const float* __restrict__ W0, const float* __restrict__ W1,
    const float* __restrict__ W2, const float* __restrict__ W3,
    u16* __restrict__ T0, u16* __restrict__ T1,
    u16* __restrict__ T2, u16* __restrict__ T3)
{
    __shared__ u16 t[64][65];
    int z = blockIdx.z;
    const float* W = (z == 0) ? W0 : (z == 1) ? W1 : (z == 2) ? W2 : W3;
    u16* O = (z == 0) ? T0 : (z == 1) ? T1 : (z == 2) ? T2 : T3;
    int r0 = blockIdx.x * 64, c0 = blockIdx.y * 64;
    int tid = threadIdx.x;
    int row = tid >> 2, seg = (tid & 3) * 16;
    #pragma unroll
    for (int i = 0; i < 16; i++)
        t[row][seg + i] = f2b(W[(size_t)(r0 + row) * 1024 + c0 + seg + i]);
    __syncthreads();
    #pragma unroll
    for (int i = 0; i < 16; i++)
        O[(size_t)(c0 + row) * 1024 + r0 + seg + i] = t[seg + i][row];
}

// ---------------------------------------------------------------------------
// 128x128-tile bf16 MFMA GEMM, C[M,N] = A[M,K] @ Bt[N,K]^T. M=4096, N=K=1024.
// Linear LDS (audited build). Dest: f32 (Cf) or bf16 (Cb), exactly one set.
// ---------------------------------------------------------------------------
__global__ __launch_bounds__(256) void gemm128(
    const u16* __restrict__ A, const u16* __restrict__ Bt,
    u16* __restrict__ Cb, float* __restrict__ Cf)
{
    constexpr int K = 1024, N = 1024;
    __shared__ u16 sA[128 * 64];
    __shared__ u16 sB[128 * 64];
    const int tid = threadIdx.x;
    const int w = tid >> 6, l = tid & 63;
    const int m0 = blockIdx.x * 128, n0 = blockIdx.y * 128;
    const int wr = w >> 1, wc = w & 1;
    const int fr = l & 15, fg = l >> 4;

    f32x4 acc[4][4] = {};

    for (int kt = 0; kt < 16; ++kt) {
        const int k0 = kt * 64;
        __syncthreads();
        uint4 va[4], vb[4];
        #pragma unroll
        for (int j = 0; j < 4; ++j) {
            int ci = j * 256 + tid;
            int row = ci >> 3, pos = (ci & 7) * 8;
            va[j] = *(const uint4*)(A  + (size_t)(m0 + row) * K + k0 + pos);
            vb[j] = *(const uint4*)(Bt + (size_t)(n0 + row) * K + k0 + pos);
        }
        #pragma unroll
        for (int j = 0; j < 4; ++j) {
            int ci = j * 256 + tid;
            int row = ci >> 3, pos = (ci & 7) * 8;
            *(uint4*)(&sA[row * 64 + pos]) = va[j];
            *(uint4*)(&sB[row * 64 + pos]) = vb[j];
        }
        __syncthreads();

        #pragma unroll
        for (int kk = 0; kk < 2; ++kk) {
            bf16x8 af[4], bf[4];
            #pragma unroll
            for (int mi = 0; mi < 4; ++mi)
                af[mi] = *(const bf16x8*)(&sA[(wr * 64 + mi * 16 + fr) * 64 + kk * 32 + fg * 8]);
            #pragma unroll
            for (int ni = 0; ni < 4; ++ni)
                bf[ni] = *(const bf16x8*)(&sB[(wc * 64 + ni * 16 + fr) * 64 + kk * 32 + fg * 8]);
            #pragma unroll
            for (int mi = 0; mi < 4; ++mi)
                #pragma unroll
                for (int ni = 0; ni < 4; ++ni)
                    acc[mi][ni] = __builtin_amdgcn_mfma_f32_16x16x32_bf16(af[mi], bf[ni], acc[mi][ni], 0, 0, 0);
        }
    }

    #pragma unroll
    for (int mi = 0; mi < 4; ++mi)
        #pragma unroll
        for (int ni = 0; ni < 4; ++ni)
            #pragma unroll
            for (int rr = 0; rr < 4; ++rr) {
                int r = m0 + wr * 64 + mi * 16 + fg * 4 + rr;
                int c = n0 + wc * 64 + ni * 16 + fr;
                size_t off = (size_t)r * N + c;
                if (Cf) Cf[off] = acc[mi][ni][rr];
                else    Cb[off] = f2b(acc[mi][ni][rr]);
            }
}

// ---------------------------------------------------------------------------
// Up-projection + partial RoPE. One wave per (b,t,h). qlat bf16 (ws);
// klat/vlat f32 (the d_out output slots). Q pre-scaled by 0.125.
// Writes Q,K,V in [B][H][T][64] bf16.
// ---------------------------------------------------------------------------
__global__ __launch_bounds__(256) void upproj(
    const u16* __restrict__ qlat, const float* __restrict__ klat,
    const float* __restrict__ vlat,
    const float* __restrict__ Wqc, const float* __restrict__ Wqe,
    const float* __restrict__ Wkc, const float* __restrict__ Wke,
    const float* __restrict__ Wv,
    u16* __restrict__ Q, u16* __restrict__ Ko, u16* __restrict__ Vo)
{
    __shared__ float wqc[2048], wqe[2048], wkc[2048], wke[2048], wv[4096];
    __shared__ float lat[4][3][64];
    int tid = threadIdx.x;
    for (int i = tid; i < 2048; i += 256) {
        wqc[i] = Wqc[i]; wqe[i] = Wqe[i];
        wkc[i] = Wkc[i]; wke[i] = Wke[i];
    }
    for (int i = tid; i < 4096; i += 256) wv[i] = Wv[i];

    int w = tid >> 6, l = tid & 63;
    int gw = blockIdx.x * 4 + w;          // 0..65535 = b*16384 + t*16 + h
    int h = gw & 15, t = (gw >> 4) & 1023, b = gw >> 14;
    size_t latoff = ((size_t)(b * 1024 + t)) * 1024 + h * 64;
    __syncthreads();
    lat[w][0][l] = b2f(qlat[latoff + l]);
    lat[w][1][l] = klat[latoff + l];
    lat[w][2][l] = vlat[latoff + l];
    __syncthreads();

    const float* wqp = (l < 32) ? (wqc + l) : (wqe + (l - 32));
    const float* wkp = (l < 32) ? (wkc + l) : (wke + (l - 32));
    const float* wvp = wv + l;
    float aq = 0.f, ak = 0.f, av = 0.f;
    #pragma unroll 8
    for (int i = 0; i < 64; i++) {
        float lq = lat[w][0][i], lk = lat[w][1][i], lv = lat[w][2][i];
        aq += lq * wqp[i * 32];
        ak += lk * wkp[i * 32];
        av += lv * wvp[i * 64];
    }
    // partial RoPE on dims 32..63: interleaved rotate-half pairs (2i,2i+1),
    // per-element frequency index (c mod 16), matching concat([freqs,freqs]).
    float pq = __shfl_xor(aq, 1);
    float pk = __shfl_xor(ak, 1);
    if (l >= 32) {
        int cp = l - 32, fi = cp & 15;
        float ang = (float)t * expf(-(float)fi * (9.210340371976184f / 16.0f));
        float cs = cosf(ang), sn = sinf(ang);
        float rq = (l & 1) ? pq : -pq;
        float rk = (l & 1) ? pk : -pk;
        aq = aq * cs + rq * sn;
        ak = ak * cs + rk * sn;
    }
    aq *= 0.125f;   // fold attention scale into Q (exact: power of two)
    size_t qoff = ((size_t)(b * 16 + h) * 1024 + t) * 64 + l;
    Q[qoff] = f2b(aq); Ko[qoff] = f2b(ak); Vo[qoff] = f2b(av);
}

// ---------------------------------------------------------------------------
// Flash-style causal MFMA attention (audited linear-LDS build).
// Block = (qt, bh): 64 Q-rows, 4 waves x 16 rows. Q pre-scaled.
// Writes Ya[b][t][h][d] bf16 ([4096][1024]).
// ---------------------------------------------------------------------------
__global__ __launch_bounds__(256) void attn(
    const u16* __restrict__ Q, const u16* __restrict__ K, const u16* __restrict__ V,
    u16* __restrict__ Y)
{
    __shared__ u16 sK[64 * 64];        // [kv][d]
    __shared__ u16 sVt[64 * 64];       // transposed: [d][kv]
    __shared__ u16 sP[4][16 * 64];     // per-wave [qrow][kv]
    int tid = threadIdx.x, w = tid >> 6, l = tid & 63;
    int qt = blockIdx.x, bh = blockIdx.y;
    int b = bh >> 4, h = bh & 15;
    int fr = l & 15, fg = l >> 4;
    int q0w = qt * 64 + w * 16;
    const size_t base = (size_t)bh * 1024 * 64;

    bf16x8 qf[2];
    #pragma unroll
    for (int kk = 0; kk < 2; kk++)
        qf[kk] = *(const bf16x8*)(Q + base + (size_t)(q0w + fr) * 64 + kk * 32 + fg * 8);

    f32x4 o[4] = {};
    float m[4], ls[4] = {0.f, 0.f, 0.f, 0.f};
    m[0] = m[1] = m[2] = m[3] = -30000.0f;

    const int vrow = tid >> 2, vseg = tid & 3;

    for (int kt = 0; kt <= qt; ++kt) {
        int kv0 = kt * 64;
        __syncthreads();
        #pragma unroll
        for (int j = 0; j < 2; ++j) {
            int ci = j * 256 + tid;
            int row = ci >> 3, pos = (ci & 7) * 8;
            uint4 vk = *(const uint4*)(K + base + (size_t)(kv0 + row) * 64 + pos);
            *(uint4*)(&sK[row * 64 + pos]) = vk;
        }
        {
            const u16* vsrc = V + base + (size_t)(kv0 + vrow) * 64 + vseg * 16;
            u16 tmp[16];
            *(uint4*)(tmp)     = *(const uint4*)vsrc;
            *(uint4*)(tmp + 8) = *(const uint4*)(vsrc + 8);
            #pragma unroll
            for (int j = 0; j < 16; j++)
                sVt[(vseg * 16 + j) * 64 + vrow] = tmp[j];
        }
        __syncthreads();

        f32x4 s[4] = {};
        #pragma unroll
        for (int kk = 0; kk < 2; kk++) {
            #pragma unroll
            for (int ni = 0; ni < 4; ni++) {
                bf16x8 kf = *(const bf16x8*)(&sK[(ni * 16 + fr) * 64 + kk * 32 + fg * 8]);
                s[ni] = __builtin_amdgcn_mfma_f32_16x16x32_bf16(qf[kk], kf, s[ni], 0, 0, 0);
            }
        }
        if (kt == qt) {
            #pragma unroll
            for (int ni = 0; ni < 4; ni++) {
                int kj = kv0 + ni * 16 + fr;
                #pragma unroll
                for (int rr = 0; rr < 4; rr++) {
                    int qi = q0w + fg * 4 + rr;
                    if (kj > qi) s[ni][rr] = -30000.0f;
                }
            }
        }
        float alpha[4];
        #pragma unroll
        for (int rr = 0; rr < 4; rr++) {
            float mx = fmaxf(fmaxf(s[0][rr], s[1][rr]), fmaxf(s[2][rr], s[3][rr]));
            mx = fmaxf(mx, __shfl_xor(mx, 1));
            mx = fmaxf(mx, __shfl_xor(mx, 2));
            mx = fmaxf(mx, __shfl_xor(mx, 4));
            mx = fmaxf(mx, __shfl_xor(mx, 8));
            float mn = fmaxf(m[rr], mx);
            alpha[rr] = __expf(m[rr] - mn);
            m[rr] = mn;
        }
        float psum[4] = {0.f, 0.f, 0.f, 0.f};
        #pragma unroll
        for (int ni = 0; ni < 4; ni++)
            #pragma unroll
            for (int rr = 0; rr < 4; rr++) {
                float p = __expf(s[ni][rr] - m[rr]);
                s[ni][rr] = p;
                psum[rr] += p;
            }
        #pragma unroll
        for (int rr = 0; rr < 4; rr++) ls[rr] = ls[rr] * alpha[rr] + psum[rr];
        #pragma unroll
        for (int ni = 0; ni < 4; ni++)
            #pragma unroll
            for (int rr = 0; rr < 4; rr++) o[ni][rr] *= alpha[rr];
        #pragma unroll
        for (int ni = 0; ni < 4; ni++)
            #pragma unroll
            for (int rr = 0; rr < 4; rr++)
                sP[w][(fg * 4 + rr) * 64 + ni * 16 + fr] = f2b(s[ni][rr]);
        __syncthreads();
        #pragma unroll
        for (int kk = 0; kk < 2; kk++) {
            bf16x8 pa = *(const bf16x8*)(&sP[w][fr * 64 + kk * 32 + fg * 8]);
            #pragma unroll
            for (int ni = 0; ni < 4; ni++) {
                bf16x8 vf = *(const bf16x8*)(&sVt[(ni * 16 + fr) * 64 + kk * 32 + fg * 8]);
                o[ni] = __builtin_amdgcn_mfma_f32_16x16x32_bf16(pa, vf, o[ni], 0, 0, 0);
            }
        }
    }

    #pragma unroll
    for (int rr = 0; rr < 4; rr++) {
        float tot = ls[rr];
        tot += __shfl_xor(tot, 1);
        tot += __shfl_xor(tot, 2);
        tot += __shfl_xor(tot, 4);
        tot += __shfl_xor(tot, 8);
        ls[rr] = 1.0f / tot;
    }
    #pragma unroll
    for (int ni = 0; ni < 4; ni++)
        #pragma unroll
        for (int rr = 0; rr < 4; rr++) {
            int qi = q0w + fg * 4 + rr;
            size_t yoff = ((size_t)(b * 1024 + qi)) * 1024 + h * 64 + ni * 16 + fr;
            Y[yoff] = f2b(o[ni][rr] * ls[rr]);
        }
}

// ---------------------------------------------------------------------------
extern "C" void kernel_launch(void* const* d_in, const int* in_sizes, int n_in,
                              void* d_out, int out_size, void* d_ws, size_t ws_size,
                              hipStream_t stream) {
    const float* x    = (const float*)d_in[0];
    const float* Wqd  = (const float*)d_in[1];
    const float* Wkd  = (const float*)d_in[2];
    const float* Wvd  = (const float*)d_in[3];
    const float* Wqc  = (const float*)d_in[4];
    const float* Wqe  = (const float*)d_in[5];
    const float* Wkc  = (const float*)d_in[6];
    const float* Wke  = (const float*)d_in[7];
    const float* Wvu  = (const float*)d_in[8];
    const float* Wc   = (const float*)d_in[9];

    float* dout     = (float*)d_out;          // f32 outputs
    float* y_out    = dout;                   // [4,1024,1024]
    float* klat_out = dout + 4194304;         // [4,1024,16,64]
    float* vlat_out = dout + 8388608;         // [4,1024,16,64]

    const size_t MiB = 1024 * 1024;
    // d_out y-region (16 MiB, written last) doubles as scratch:
    //   phase A (until gemms done): xb @ +0 (8M), WqdT @ +8M, WkdT @ +10M, WvdT @ +12M
    //   phase B (upproj -> attn):   Qw @ +0 (8M), Kw @ +8M (8M)
    char* db = (char*)d_out;
    u16* xb   = (u16*)db;
    u16* WqdT = (u16*)(db + 8  * MiB);
    u16* WkdT = (u16*)(db + 10 * MiB);
    u16* WvdT = (u16*)(db + 12 * MiB);
    u16* Qw   = (u16*)db;
    u16* Kw   = (u16*)(db + 8 * MiB);

    // d_ws: 18 MiB total (known safe: R5 proved ws_size >= 24 MiB)
    char* ws = (char*)d_ws;
    u16* WcT  = (u16*)ws;                     // 2 MiB  [live -> final gemm]
    u16* qlat = (u16*)(ws + 2 * MiB);         // 8 MiB  [gemm -> upproj]
    u16* Ya   = (u16*)(ws + 2 * MiB);         // overlay [attn -> final gemm]
    u16* Vw   = (u16*)(ws + 10 * MiB);        // 8 MiB  [upproj -> attn]

    convert_x<<<dim3(2048), 256, 0, stream>>>(x, xb);
    transpose4<<<dim3(16, 16, 4), 256, 0, stream>>>(Wqd, Wkd, Wvd, Wc,
                                                    WqdT, WkdT, WvdT, WcT);
    gemm128<<<dim3(32, 8), 256, 0, stream>>>(xb, WqdT, qlat, nullptr);
    gemm128<<<dim3(32, 8), 256, 0, stream>>>(xb, WkdT, nullptr, klat_out);
    gemm128<<<dim3(32, 8), 256, 0, stream>>>(xb, WvdT, nullptr, vlat_out);
    upproj<<<dim3(16384), 256, 0, stream>>>(qlat, klat_out, vlat_out,
                                            Wqc, Wqe, Wkc, Wke, Wvu, Qw, Kw, Vw);
    attn<<<dim3(16, 64), 256, 0, stream>>>(Qw, Kw, Vw, Ya);
    gemm128<<<dim3(32, 8), 256, 0, stream>>>(Ya, WcT, nullptr, y_out);
}

// Round 7
// 204.960 us; speedup vs baseline: 1.4834x; 1.4834x over previous
//
#include <hip/hip_runtime.h>

typedef unsigned short u16;
typedef unsigned int   u32;
typedef __bf16 bf16x8 __attribute__((ext_vector_type(8)));
typedef float  f32x4  __attribute__((ext_vector_type(4)));

// Contract (established R0-R6): inputs f32, outputs f32.
// d_out = y[4M f32] | k_lat[4M f32] | v_lat[4M f32]. ws_size >= 24 MiB.

__device__ __forceinline__ float b2f(u16 u) {
    u32 x = ((u32)u) << 16; float f; __builtin_memcpy(&f, &x, 4); return f;
}
__device__ __forceinline__ u16 f2b(float f) {
    u32 x; __builtin_memcpy(&x, &f, 4);
    u32 r = x + 0x7FFFu + ((x >> 16) & 1u);
    return (u16)(r >> 16);
}

#define GLD_LDS16(src, dst) \
  __builtin_amdgcn_global_load_lds((const __attribute__((address_space(1))) unsigned int*)(src), \
                                   (__attribute__((address_space(3))) unsigned int*)(dst), 16, 0, 0)

// ---------------------------------------------------------------------------
// x f32 [4096][1024] -> bf16 copy (lives in d_out y-region scratch)
// ---------------------------------------------------------------------------
__global__ __launch_bounds__(256) void convert_x(
    const float* __restrict__ x, u16* __restrict__ xb)
{
    int i0 = (blockIdx.x * 256 + threadIdx.x) * 8;
    #pragma unroll
    for (int j = 0; j < 8; j++) xb[i0 + j] = f2b(x[i0 + j]);
}

// ---------------------------------------------------------------------------
// Transpose 4 f32 [1024][1024] weights into bf16 WT[n][k] = W[k][n]
// ---------------------------------------------------------------------------
__global__ __launch_bounds__(256) void transpose4(
    const float* __restrict__ W0, const float* __restrict__ W1,
    const float* __restrict__ W2, const float* __restrict__ W3,
    u16* __restrict__ T0, u16* __restrict__ T1,
    u16* __restrict__ T2, u16* __restrict__ T3)
{
    __shared__ u16 t[64][65];
    int z = blockIdx.z;
    const float* W = (z == 0) ? W0 : (z == 1) ? W1 : (z == 2) ? W2 : W3;
    u16* O = (z == 0) ? T0 : (z == 1) ? T1 : (z == 2) ? T2 : T3;
    int r0 = blockIdx.x * 64, c0 = blockIdx.y * 64;
    int tid = threadIdx.x;
    int row = tid >> 2, seg = (tid & 3) * 16;
    #pragma unroll
    for (int i = 0; i < 16; i++)
        t[row][seg + i] = f2b(W[(size_t)(r0 + row) * 1024 + c0 + seg + i]);
    __syncthreads();
    #pragma unroll
    for (int i = 0; i < 16; i++)
        O[(size_t)(c0 + row) * 1024 + r0 + seg + i] = t[seg + i][row];
}

// ---------------------------------------------------------------------------
// 128x128-tile bf16 MFMA GEMM (m97 recipe): global_load_lds width-16 staging
// with both-sides XOR swizzle (LDS dest linear; source k-offset pre-swizzled
// by 16B*((chunk)^(row&7)); read applies same XOR). C = A @ Bt^T.
// Dest: f32 (Cf) or bf16 (Cb).
// ---------------------------------------------------------------------------
__global__ __launch_bounds__(256) void gemm128(
    const u16* __restrict__ A, const u16* __restrict__ Bt,
    u16* __restrict__ Cb, float* __restrict__ Cf)
{
    constexpr int K = 1024, N = 1024;
    __shared__ __align__(16) char sA[16384];
    __shared__ __align__(16) char sB[16384];
    const int tid = threadIdx.x;
    const int w = tid >> 6, l = tid & 63;
    const int m0 = blockIdx.x * 128, n0 = blockIdx.y * 128;
    const int wr = w >> 1, wc = w & 1;
    const int fr = l & 15, fg = l >> 4;

    // lane l stages 16B chunk (l&7) of row (l>>3) per 8-row group; source
    // chunk pre-swizzled so the swizzled read below returns linear data.
    const int skb = (((l & 7) * 16) ^ ((l >> 3) << 4)) >> 1;  // element offset
    const int srow = l >> 3;

    f32x4 acc[4][4] = {};

    for (int kt = 0; kt < 16; ++kt) {
        const int k0 = kt * 64;
        if (kt > 0) __syncthreads();   // all waves done reading previous tile
        #pragma unroll
        for (int ci = 0; ci < 4; ++ci) {
            int c = w + ci * 4;
            int row = c * 8 + srow;
            GLD_LDS16(A  + (size_t)(m0 + row) * K + k0 + skb, sA + c * 1024);
            GLD_LDS16(Bt + (size_t)(n0 + row) * K + k0 + skb, sB + c * 1024);
        }
        asm volatile("s_waitcnt vmcnt(0)" ::: "memory");
        __syncthreads();

        #pragma unroll
        for (int kk = 0; kk < 2; ++kk) {
            bf16x8 af[4], bf[4];
            #pragma unroll
            for (int mi = 0; mi < 4; ++mi) {
                int row = wr * 64 + mi * 16 + fr;
                int off = row * 128 + ((kk * 64 + fg * 16) ^ ((fr & 7) << 4));
                af[mi] = *(const bf16x8*)(sA + off);
            }
            #pragma unroll
            for (int ni = 0; ni < 4; ++ni) {
                int row = wc * 64 + ni * 16 + fr;
                int off = row * 128 + ((kk * 64 + fg * 16) ^ ((fr & 7) << 4));
                bf[ni] = *(const bf16x8*)(sB + off);
            }
            #pragma unroll
            for (int mi = 0; mi < 4; ++mi)
                #pragma unroll
                for (int ni = 0; ni < 4; ++ni)
                    acc[mi][ni] = __builtin_amdgcn_mfma_f32_16x16x32_bf16(af[mi], bf[ni], acc[mi][ni], 0, 0, 0);
        }
    }

    #pragma unroll
    for (int mi = 0; mi < 4; ++mi)
        #pragma unroll
        for (int ni = 0; ni < 4; ++ni)
            #pragma unroll
            for (int rr = 0; rr < 4; ++rr) {
                int r = m0 + wr * 64 + mi * 16 + fg * 4 + rr;
                int c = n0 + wc * 64 + ni * 16 + fr;
                size_t off = (size_t)r * N + c;
                if (Cf) Cf[off] = acc[mi][ni][rr];
                else    Cb[off] = f2b(acc[mi][ni][rr]);
            }
}

// ---------------------------------------------------------------------------
// Up-projection + fused partial RoPE as batched per-head MFMA GEMM.
// grid (64 row-chunks, 16 heads), block 192 = 3 waves; wave w -> matrix
// (0=Q, 1=K, 2=V). Per wave: [64 rows x 64 lat] @ [64 lat x 64 cols].
// RoPE epilogue: C-frag col = ni*16+fr; for cols>=32, freq index = fr,
// rotate-half partner = col^1 = lane fr^1 (shfl_xor 1). Q pre-scaled 0.125.
// Outputs [B][H][T][64] bf16.
// ---------------------------------------------------------------------------
__global__ __launch_bounds__(192) void upproj_mfma(
    const u16* __restrict__ qlat, const float* __restrict__ klat,
    const float* __restrict__ vlat,
    const float* __restrict__ Wqc, const float* __restrict__ Wqe,
    const float* __restrict__ Wkc, const float* __restrict__ Wke,
    const float* __restrict__ Wv,
    u16* __restrict__ Qo, u16* __restrict__ Ko, u16* __restrict__ Vo)
{
    // k-chunk-major weight tiles: sW[mat][k>>3][n][k&7] -> B-frag reads are
    // 16 consecutive 16B chunks per fg-group => conflict-free.
    __shared__ __align__(16) u16 sW[3][8][64][8];
    const int tid = threadIdx.x, w = tid / 64, l = tid & 63;
    const int h = blockIdx.y;
    const int m0 = blockIdx.x * 64;
    const int fr = l & 15, fg = l >> 4;

    for (int e = l; e < 4096; e += 64) {
        int k = e >> 6, n = e & 63;
        float v;
        if (w == 2)      v = Wv[k * 64 + n];
        else if (w == 0) v = (n < 32) ? Wqc[k * 32 + n] : Wqe[k * 32 + n - 32];
        else             v = (n < 32) ? Wkc[k * 32 + n] : Wke[k * 32 + n - 32];
        sW[w][k >> 3][n][k & 7] = f2b(v);
    }
    __syncthreads();

    // A fragments: rows m0 + mi*16 + fr, k-slice kk*32 + fg*8 .. +8
    bf16x8 af[4][2];
    if (w == 0) {
        #pragma unroll
        for (int mi = 0; mi < 4; ++mi)
            #pragma unroll
            for (int kk = 0; kk < 2; ++kk)
                af[mi][kk] = *(const bf16x8*)(qlat + (size_t)(m0 + mi * 16 + fr) * 1024 + h * 64 + kk * 32 + fg * 8);
    } else {
        const float* L = (w == 1) ? klat : vlat;
        #pragma unroll
        for (int mi = 0; mi < 4; ++mi)
            #pragma unroll
            for (int kk = 0; kk < 2; ++kk) {
                const float* p = L + (size_t)(m0 + mi * 16 + fr) * 1024 + h * 64 + kk * 32 + fg * 8;
                float4 x0 = *(const float4*)p;
                float4 x1 = *(const float4*)(p + 4);
                union { bf16x8 v; u16 u[8]; } tmp;
                tmp.u[0] = f2b(x0.x); tmp.u[1] = f2b(x0.y);
                tmp.u[2] = f2b(x0.z); tmp.u[3] = f2b(x0.w);
                tmp.u[4] = f2b(x1.x); tmp.u[5] = f2b(x1.y);
                tmp.u[6] = f2b(x1.z); tmp.u[7] = f2b(x1.w);
                af[mi][kk] = tmp.v;
            }
    }

    bf16x8 bfr[4][2];
    #pragma unroll
    for (int ni = 0; ni < 4; ++ni)
        #pragma unroll
        for (int kk = 0; kk < 2; ++kk)
            bfr[ni][kk] = *(const bf16x8*)&sW[w][kk * 4 + fg][ni * 16 + fr][0];

    f32x4 acc[4][4] = {};
    #pragma unroll
    for (int kk = 0; kk < 2; ++kk)
        #pragma unroll
        for (int mi = 0; mi < 4; ++mi)
            #pragma unroll
            for (int ni = 0; ni < 4; ++ni)
                acc[mi][ni] = __builtin_amdgcn_mfma_f32_16x16x32_bf16(af[mi][kk], bfr[ni][kk], acc[mi][ni], 0, 0, 0);

    // epilogue: RoPE (Q,K waves) + scale (Q) + store
    const bool rope = (w < 2);
    const float qscale = (w == 0) ? 0.125f : 1.0f;
    const float rf = __expf(-(float)fr * 0.5756462732485115f);  // ln(1e4)/16
    u16* O = (w == 0) ? Qo : (w == 1) ? Ko : Vo;
    const int b = m0 >> 10, tbase = m0 & 1023;
    const size_t obase = ((size_t)(b * 16 + h)) << 16;

    #pragma unroll
    for (int mi = 0; mi < 4; ++mi) {
        #pragma unroll
        for (int rr = 0; rr < 4; ++rr) {
            int t = tbase + mi * 16 + fg * 4 + rr;
            float sn = 0.f, cs = 0.f;
            if (rope) {
                float ang = (float)t * rf;
                sn = __sinf(ang); cs = __cosf(ang);
            }
            #pragma unroll
            for (int ni = 0; ni < 4; ++ni) {
                float a = acc[mi][ni][rr];
                float p = __shfl_xor(a, 1);
                if (rope && ni >= 2)
                    a = a * cs + ((fr & 1) ? p : -p) * sn;
                a *= qscale;
                O[obase + (size_t)t * 64 + ni * 16 + fr] = f2b(a);
            }
        }
    }
}

// ---------------------------------------------------------------------------
// Flash-style causal MFMA attention (audited linear-LDS build).
// Block = (qt, bh): 64 Q-rows, 4 waves x 16 rows. Q pre-scaled.
// Writes Ya[b][t][h][d] bf16 ([4096][1024]).
// ---------------------------------------------------------------------------
__global__ __launch_bounds__(256) void attn(
    const u16* __restrict__ Q, const u16* __restrict__ K, const u16* __restrict__ V,
    u16* __restrict__ Y)
{
    __shared__ u16 sK[64 * 64];        // [kv][d]
    __shared__ u16 sVt[64 * 64];       // transposed: [d][kv]
    __shared__ u16 sP[4][16 * 64];     // per-wave [qrow][kv]
    int tid = threadIdx.x, w = tid >> 6, l = tid & 63;
    int qt = blockIdx.x, bh = blockIdx.y;
    int b = bh >> 4, h = bh & 15;
    int fr = l & 15, fg = l >> 4;
    int q0w = qt * 64 + w * 16;
    const size_t base = (size_t)bh * 1024 * 64;

    bf16x8 qf[2];
    #pragma unroll
    for (int kk = 0; kk < 2; kk++)
        qf[kk] = *(const bf16x8*)(Q + base + (size_t)(q0w + fr) * 64 + kk * 32 + fg * 8);

    f32x4 o[4] = {};
    float m[4], ls[4] = {0.f, 0.f, 0.f, 0.f};
    m[0] = m[1] = m[2] = m[3] = -30000.0f;

    const int vrow = tid >> 2, vseg = tid & 3;

    for (int kt = 0; kt <= qt; ++kt) {
        int kv0 = kt * 64;
        __syncthreads();
        #pragma unroll
        for (int j = 0; j < 2; ++j) {
            int ci = j * 256 + tid;
            int row = ci >> 3, pos = (ci & 7) * 8;
            uint4 vk = *(const uint4*)(K + base + (size_t)(kv0 + row) * 64 + pos);
            *(uint4*)(&sK[row * 64 + pos]) = vk;
        }
        {
            const u16* vsrc = V + base + (size_t)(kv0 + vrow) * 64 + vseg * 16;
            u16 tmp[16];
            *(uint4*)(tmp)     = *(const uint4*)vsrc;
            *(uint4*)(tmp + 8) = *(const uint4*)(vsrc + 8);
            #pragma unroll
            for (int j = 0; j < 16; j++)
                sVt[(vseg * 16 + j) * 64 + vrow] = tmp[j];
        }
        __syncthreads();

        f32x4 s[4] = {};
        #pragma unroll
        for (int kk = 0; kk < 2; kk++) {
            #pragma unroll
            for (int ni = 0; ni < 4; ni++) {
                bf16x8 kf = *(const bf16x8*)(&sK[(ni * 16 + fr) * 64 + kk * 32 + fg * 8]);
                s[ni] = __builtin_amdgcn_mfma_f32_16x16x32_bf16(qf[kk], kf, s[ni], 0, 0, 0);
            }
        }
        if (kt == qt) {
            #pragma unroll
            for (int ni = 0; ni < 4; ni++) {
                int kj = kv0 + ni * 16 + fr;
                #pragma unroll
                for (int rr = 0; rr < 4; rr++) {
                    int qi = q0w + fg * 4 + rr;
                    if (kj > qi) s[ni][rr] = -30000.0f;
                }
            }
        }
        float alpha[4];
        #pragma unroll
        for (int rr = 0; rr < 4; rr++) {
            float mx = fmaxf(fmaxf(s[0][rr], s[1][rr]), fmaxf(s[2][rr], s[3][rr]));
            mx = fmaxf(mx, __shfl_xor(mx, 1));
            mx = fmaxf(mx, __shfl_xor(mx, 2));
            mx = fmaxf(mx, __shfl_xor(mx, 4));
            mx = fmaxf(mx, __shfl_xor(mx, 8));
            float mn = fmaxf(m[rr], mx);
            alpha[rr] = __expf(m[rr] - mn);
            m[rr] = mn;
        }
        float psum[4] = {0.f, 0.f, 0.f, 0.f};
        #pragma unroll
        for (int ni = 0; ni < 4; ni++)
            #pragma unroll
            for (int rr = 0; rr < 4; rr++) {
                float p = __expf(s[ni][rr] - m[rr]);
                s[ni][rr] = p;
                psum[rr] += p;
            }
        #pragma unroll
        for (int rr = 0; rr < 4; rr++) ls[rr] = ls[rr] * alpha[rr] + psum[rr];
        #pragma unroll
        for (int ni = 0; ni < 4; ni++)
            #pragma unroll
            for (int rr = 0; rr < 4; rr++) o[ni][rr] *= alpha[rr];
        #pragma unroll
        for (int ni = 0; ni < 4; ni++)
            #pragma unroll
            for (int rr = 0; rr < 4; rr++)
                sP[w][(fg * 4 + rr) * 64 + ni * 16 + fr] = f2b(s[ni][rr]);
        __syncthreads();
        #pragma unroll
        for (int kk = 0; kk < 2; kk++) {
            bf16x8 pa = *(const bf16x8*)(&sP[w][fr * 64 + kk * 32 + fg * 8]);
            #pragma unroll
            for (int ni = 0; ni < 4; ni++) {
                bf16x8 vf = *(const bf16x8*)(&sVt[(ni * 16 + fr) * 64 + kk * 32 + fg * 8]);
                o[ni] = __builtin_amdgcn_mfma_f32_16x16x32_bf16(pa, vf, o[ni], 0, 0, 0);
            }
        }
    }

    #pragma unroll
    for (int rr = 0; rr < 4; rr++) {
        float tot = ls[rr];
        tot += __shfl_xor(tot, 1);
        tot += __shfl_xor(tot, 2);
        tot += __shfl_xor(tot, 4);
        tot += __shfl_xor(tot, 8);
        ls[rr] = 1.0f / tot;
    }
    #pragma unroll
    for (int ni = 0; ni < 4; ni++)
        #pragma unroll
        for (int rr = 0; rr < 4; rr++) {
            int qi = q0w + fg * 4 + rr;
            size_t yoff = ((size_t)(b * 1024 + qi)) * 1024 + h * 64 + ni * 16 + fr;
            Y[yoff] = f2b(o[ni][rr] * ls[rr]);
        }
}

// ---------------------------------------------------------------------------
extern "C" void kernel_launch(void* const* d_in, const int* in_sizes, int n_in,
                              void* d_out, int out_size, void* d_ws, size_t ws_size,
                              hipStream_t stream) {
    const float* x    = (const float*)d_in[0];
    const float* Wqd  = (const float*)d_in[1];
    const float* Wkd  = (const float*)d_in[2];
    const float* Wvd  = (const float*)d_in[3];
    const float* Wqc  = (const float*)d_in[4];
    const float* Wqe  = (const float*)d_in[5];
    const float* Wkc  = (const float*)d_in[6];
    const float* Wke  = (const float*)d_in[7];
    const float* Wvu  = (const float*)d_in[8];
    const float* Wc   = (const float*)d_in[9];

    float* dout     = (float*)d_out;          // f32 outputs
    float* y_out    = dout;                   // [4,1024,1024]
    float* klat_out = dout + 4194304;         // [4,1024,16,64]
    float* vlat_out = dout + 8388608;         // [4,1024,16,64]

    const size_t MiB = 1024 * 1024;
    // d_out y-region (16 MiB, written last) doubles as scratch:
    //   phase A: xb @ +0 (8M), WqdT @ +8M, WkdT @ +10M, WvdT @ +12M, (free @ +14M)
    //   phase B: Qw @ +0 (8M), Kw @ +8M (8M)
    char* db = (char*)d_out;
    u16* xb   = (u16*)db;
    u16* WqdT = (u16*)(db + 8  * MiB);
    u16* WkdT = (u16*)(db + 10 * MiB);
    u16* WvdT = (u16*)(db + 12 * MiB);
    u16* Qw   = (u16*)db;
    u16* Kw   = (u16*)(db + 8 * MiB);

    // d_ws: 18 MiB total (R5 proved ws_size >= 24 MiB)
    char* ws = (char*)d_ws;
    u16* WcT  = (u16*)ws;                     // 2 MiB  [-> final gemm]
    u16* qlat = (u16*)(ws + 2 * MiB);         // 8 MiB  [gemm -> upproj]
    u16* Ya   = (u16*)(ws + 2 * MiB);         // overlay [attn -> final gemm]
    u16* Vw   = (u16*)(ws + 10 * MiB);        // 8 MiB  [upproj -> attn]

    convert_x<<<dim3(2048), 256, 0, stream>>>(x, xb);
    transpose4<<<dim3(16, 16, 4), 256, 0, stream>>>(Wqd, Wkd, Wvd, Wc,
                                                    WqdT, WkdT, WvdT, WcT);
    gemm128<<<dim3(32, 8), 256, 0, stream>>>(xb, WqdT, qlat, nullptr);
    gemm128<<<dim3(32, 8), 256, 0, stream>>>(xb, WkdT, nullptr, klat_out);
    gemm128<<<dim3(32, 8), 256, 0, stream>>>(xb, WvdT, nullptr, vlat_out);
    upproj_mfma<<<dim3(64, 16), 192, 0, stream>>>(qlat, klat_out, vlat_out,
                                                  Wqc, Wqe, Wkc, Wke, Wvu,
                                                  Qw, Kw, Vw);
    attn<<<dim3(16, 64), 256, 0, stream>>>(Qw, Kw, Vw, Ya);
    gemm128<<<dim3(32, 8), 256, 0, stream>>>(Ya, WcT, nullptr, y_out);
}

// Round 8
// 126.836 us; speedup vs baseline: 2.3971x; 1.6159x over previous
//
#include <hip/hip_runtime.h>

typedef unsigned short u16;
typedef unsigned int   u32;
typedef __bf16 bf16x8 __attribute__((ext_vector_type(8)));
typedef float  f32x4  __attribute__((ext_vector_type(4)));

// Contract (established R0-R6): inputs f32, outputs f32.
// d_out = y[4M f32] | k_lat[4M f32] | v_lat[4M f32]. ws_size >= 24 MiB.

__device__ __forceinline__ float b2f(u16 u) {
    u32 x = ((u32)u) << 16; float f; __builtin_memcpy(&f, &x, 4); return f;
}
__device__ __forceinline__ u16 f2b(float f) {
    u32 x; __builtin_memcpy(&x, &f, 4);
    u32 r = x + 0x7FFFu + ((x >> 16) & 1u);
    return (u16)(r >> 16);
}

#define GLD_LDS16(src, dst) \
  __builtin_amdgcn_global_load_lds((const __attribute__((address_space(1))) unsigned int*)(src), \
                                   (__attribute__((address_space(3))) unsigned int*)(dst), 16, 0, 0)

// ---------------------------------------------------------------------------
// x f32 [4096][1024] -> bf16 copy (lives in d_out y-region scratch)
// ---------------------------------------------------------------------------
__global__ __launch_bounds__(256) void convert_x(
    const float* __restrict__ x, u16* __restrict__ xb)
{
    int i0 = (blockIdx.x * 256 + threadIdx.x) * 8;
    #pragma unroll
    for (int j = 0; j < 8; j++) xb[i0 + j] = f2b(x[i0 + j]);
}

// ---------------------------------------------------------------------------
// Transpose 4 f32 [1024][1024] weights into bf16 WT[n][k] = W[k][n]
// ---------------------------------------------------------------------------
__global__ __launch_bounds__(256) void transpose4(
    const float* __restrict__ W0, const float* __restrict__ W1,
    const float* __restrict__ W2, const float* __restrict__ W3,
    u16* __restrict__ T0, u16* __restrict__ T1,
    u16* __restrict__ T2, u16* __restrict__ T3)
{
    __shared__ u16 t[64][65];
    int z = blockIdx.z;
    const float* W = (z == 0) ? W0 : (z == 1) ? W1 : (z == 2) ? W2 : W3;
    u16* O = (z == 0) ? T0 : (z == 1) ? T1 : (z == 2) ? T2 : T3;
    int r0 = blockIdx.x * 64, c0 = blockIdx.y * 64;
    int tid = threadIdx.x;
    int row = tid >> 2, seg = (tid & 3) * 16;
    #pragma unroll
    for (int i = 0; i < 16; i++)
        t[row][seg + i] = f2b(W[(size_t)(r0 + row) * 1024 + c0 + seg + i]);
    __syncthreads();
    #pragma unroll
    for (int i = 0; i < 16; i++)
        O[(size_t)(c0 + row) * 1024 + r0 + seg + i] = t[seg + i][row];
}

// ---------------------------------------------------------------------------
// 128x128-tile bf16 MFMA GEMM body (m97 recipe): global_load_lds width-16
// staging, both-sides XOR swizzle. C = A @ Bt^T, M=4096, N=K=1024.
// ---------------------------------------------------------------------------
#define GEMM_BODY(A_, Bt_, STORE)                                              \
    constexpr int K = 1024, N = 1024;                                          \
    __shared__ __align__(16) char sA[16384];                                   \
    __shared__ __align__(16) char sB[16384];                                   \
    const int tid = threadIdx.x;                                               \
    const int w = tid >> 6, l = tid & 63;                                      \
    const int m0 = blockIdx.x * 128, n0 = blockIdx.y * 128;                    \
    const int wr = w >> 1, wc = w & 1;                                         \
    const int fr = l & 15, fg = l >> 4;                                        \
    const int skb = (((l & 7) * 16) ^ ((l >> 3) << 4)) >> 1;                   \
    const int srow = l >> 3;                                                   \
    f32x4 acc[4][4] = {};                                                      \
    for (int kt = 0; kt < 16; ++kt) {                                          \
        const int k0 = kt * 64;                                                \
        if (kt > 0) __syncthreads();                                           \
        _Pragma("unroll")                                                      \
        for (int ci = 0; ci < 4; ++ci) {                                       \
            int c = w + ci * 4;                                                \
            int row = c * 8 + srow;                                            \
            GLD_LDS16(A_  + (size_t)(m0 + row) * K + k0 + skb, sA + c * 1024); \
            GLD_LDS16(Bt_ + (size_t)(n0 + row) * K + k0 + skb, sB + c * 1024); \
        }                                                                      \
        asm volatile("s_waitcnt vmcnt(0)" ::: "memory");                       \
        __syncthreads();                                                       \
        _Pragma("unroll")                                                      \
        for (int kk = 0; kk < 2; ++kk) {                                       \
            bf16x8 af[4], bf[4];                                               \
            _Pragma("unroll")                                                  \
            for (int mi = 0; mi < 4; ++mi) {                                   \
                int row = wr * 64 + mi * 16 + fr;                              \
                int off = row * 128 + ((kk * 64 + fg * 16) ^ ((fr & 7) << 4)); \
                af[mi] = *(const bf16x8*)(sA + off);                           \
            }                                                                  \
            _Pragma("unroll")                                                  \
            for (int ni = 0; ni < 4; ++ni) {                                   \
                int row = wc * 64 + ni * 16 + fr;                              \
                int off = row * 128 + ((kk * 64 + fg * 16) ^ ((fr & 7) << 4)); \
                bf[ni] = *(const bf16x8*)(sB + off);                           \
            }                                                                  \
            _Pragma("unroll")                                                  \
            for (int mi = 0; mi < 4; ++mi)                                     \
                _Pragma("unroll")                                              \
                for (int ni = 0; ni < 4; ++ni)                                 \
                    acc[mi][ni] = __builtin_amdgcn_mfma_f32_16x16x32_bf16(     \
                        af[mi], bf[ni], acc[mi][ni], 0, 0, 0);                 \
        }                                                                      \
    }                                                                          \
    _Pragma("unroll")                                                          \
    for (int mi = 0; mi < 4; ++mi)                                             \
        _Pragma("unroll")                                                      \
        for (int ni = 0; ni < 4; ++ni)                                         \
            _Pragma("unroll")                                                  \
            for (int rr = 0; rr < 4; ++rr) {                                   \
                int r = m0 + wr * 64 + mi * 16 + fg * 4 + rr;                  \
                int c = n0 + wc * 64 + ni * 16 + fr;                           \
                size_t off = (size_t)r * N + c;                                \
                float v = acc[mi][ni][rr];                                     \
                STORE;                                                         \
            }

// Down-projection: 3 GEMMs in one dispatch (z); z0 -> bf16 qlat, z1/z2 -> f32.
__global__ __launch_bounds__(256) void gemm128_down(
    const u16* __restrict__ A,
    const u16* __restrict__ Bt0, const u16* __restrict__ Bt1, const u16* __restrict__ Bt2,
    u16* __restrict__ Cb, float* __restrict__ Cf1, float* __restrict__ Cf2)
{
    const int z = blockIdx.z;
    const u16* Bt = (z == 0) ? Bt0 : (z == 1) ? Bt1 : Bt2;
    float* Cf = (z == 1) ? Cf1 : Cf2;
    GEMM_BODY(A, Bt, { if (z == 0) Cb[off] = f2b(v); else Cf[off] = v; })
}

// Out-projection: bf16 A x bf16 Bt -> f32 C.
__global__ __launch_bounds__(256) void gemm128_out(
    const u16* __restrict__ A, const u16* __restrict__ Bt, float* __restrict__ Cf)
{
    GEMM_BODY(A, Bt, { Cf[off] = v; })
}

// ---------------------------------------------------------------------------
// Up-projection + fused partial RoPE as batched per-head MFMA GEMM.
// grid (64, 16), block 192 = 3 waves: w0=Q (RoPE+scale), w1=K (RoPE),
// w2=V (written TRANSPOSED: Vt[b][h][d][t], 4 consecutive t per 8B store).
// ---------------------------------------------------------------------------
__global__ __launch_bounds__(192) void upproj_mfma(
    const u16* __restrict__ qlat, const float* __restrict__ klat,
    const float* __restrict__ vlat,
    const float* __restrict__ Wqc, const float* __restrict__ Wqe,
    const float* __restrict__ Wkc, const float* __restrict__ Wke,
    const float* __restrict__ Wv,
    u16* __restrict__ Qo, u16* __restrict__ Ko, u16* __restrict__ Vto)
{
    __shared__ __align__(16) u16 sW[3][8][64][8];   // k-chunk-major
    const int tid = threadIdx.x, w = tid / 64, l = tid & 63;
    const int h = blockIdx.y;
    const int m0 = blockIdx.x * 64;
    const int fr = l & 15, fg = l >> 4;

    for (int e = l; e < 4096; e += 64) {
        int k = e >> 6, n = e & 63;
        float v;
        if (w == 2)      v = Wv[k * 64 + n];
        else if (w == 0) v = (n < 32) ? Wqc[k * 32 + n] : Wqe[k * 32 + n - 32];
        else             v = (n < 32) ? Wkc[k * 32 + n] : Wke[k * 32 + n - 32];
        sW[w][k >> 3][n][k & 7] = f2b(v);
    }
    __syncthreads();

    bf16x8 af[4][2];
    if (w == 0) {
        #pragma unroll
        for (int mi = 0; mi < 4; ++mi)
            #pragma unroll
            for (int kk = 0; kk < 2; ++kk)
                af[mi][kk] = *(const bf16x8*)(qlat + (size_t)(m0 + mi * 16 + fr) * 1024 + h * 64 + kk * 32 + fg * 8);
    } else {
        const float* L = (w == 1) ? klat : vlat;
        #pragma unroll
        for (int mi = 0; mi < 4; ++mi)
            #pragma unroll
            for (int kk = 0; kk < 2; ++kk) {
                const float* p = L + (size_t)(m0 + mi * 16 + fr) * 1024 + h * 64 + kk * 32 + fg * 8;
                float4 x0 = *(const float4*)p;
                float4 x1 = *(const float4*)(p + 4);
                union { bf16x8 v; u16 u[8]; } tmp;
                tmp.u[0] = f2b(x0.x); tmp.u[1] = f2b(x0.y);
                tmp.u[2] = f2b(x0.z); tmp.u[3] = f2b(x0.w);
                tmp.u[4] = f2b(x1.x); tmp.u[5] = f2b(x1.y);
                tmp.u[6] = f2b(x1.z); tmp.u[7] = f2b(x1.w);
                af[mi][kk] = tmp.v;
            }
    }

    bf16x8 bfr[4][2];
    #pragma unroll
    for (int ni = 0; ni < 4; ++ni)
        #pragma unroll
        for (int kk = 0; kk < 2; ++kk)
            bfr[ni][kk] = *(const bf16x8*)&sW[w][kk * 4 + fg][ni * 16 + fr][0];

    f32x4 acc[4][4] = {};
    #pragma unroll
    for (int kk = 0; kk < 2; ++kk)
        #pragma unroll
        for (int mi = 0; mi < 4; ++mi)
            #pragma unroll
            for (int ni = 0; ni < 4; ++ni)
                acc[mi][ni] = __builtin_amdgcn_mfma_f32_16x16x32_bf16(af[mi][kk], bfr[ni][kk], acc[mi][ni], 0, 0, 0);

    const int b = m0 >> 10, tbase = m0 & 1023;
    const size_t obase = ((size_t)(b * 16 + h)) << 16;

    if (w == 2) {
        // V: write transposed Vt[d][t]; rr=0..3 are consecutive t -> 8B store
        #pragma unroll
        for (int mi = 0; mi < 4; ++mi)
            #pragma unroll
            for (int ni = 0; ni < 4; ++ni) {
                union { u16 u[4]; uint2 v; } pk;
                #pragma unroll
                for (int rr = 0; rr < 4; ++rr) pk.u[rr] = f2b(acc[mi][ni][rr]);
                int t0 = tbase + mi * 16 + fg * 4;
                int d = ni * 16 + fr;
                *(uint2*)(Vto + obase + (size_t)d * 1024 + t0) = pk.v;
            }
    } else {
        const float qscale = (w == 0) ? 0.125f : 1.0f;
        const float rf = __expf(-(float)fr * 0.5756462732485115f);  // ln(1e4)/16
        u16* O = (w == 0) ? Qo : Ko;
        #pragma unroll
        for (int mi = 0; mi < 4; ++mi) {
            #pragma unroll
            for (int rr = 0; rr < 4; ++rr) {
                int t = tbase + mi * 16 + fg * 4 + rr;
                float ang = (float)t * rf;
                float sn = __sinf(ang), cs = __cosf(ang);
                #pragma unroll
                for (int ni = 0; ni < 4; ++ni) {
                    float a = acc[mi][ni][rr];
                    float p = __shfl_xor(a, 1);
                    if (ni >= 2)
                        a = a * cs + ((fr & 1) ? p : -p) * sn;
                    a *= qscale;
                    O[obase + (size_t)t * 64 + ni * 16 + fr] = f2b(a);
                }
            }
        }
    }
}

// ---------------------------------------------------------------------------
// Flash-style causal MFMA attention, v2:
//  - grid (bh=64, p=8); block handles Q-tiles qtA=p and qtB=15-p (balanced 17
//    tile-computes; all p-blocks of a bh on one XCD since 64 % 8 == 0)
//  - K and Vt (pre-transposed by upproj) staged via swizzled global_load_lds,
//    double-buffered (2-phase); conflict-free swizzled ds_read_b128
//  - sP swizzled both sides
// ---------------------------------------------------------------------------
__global__ __launch_bounds__(256) void attn(
    const u16* __restrict__ Q, const u16* __restrict__ K,
    const u16* __restrict__ Vt, u16* __restrict__ Y)
{
    __shared__ __align__(16) char sK[2][8192];
    __shared__ __align__(16) char sV[2][8192];
    __shared__ __align__(16) char sP[4][2048];
    const int tid = threadIdx.x, w = tid >> 6, l = tid & 63;
    const int bh = blockIdx.x, p = blockIdx.y;
    const int qtA = p, qtB = 15 - p;
    const int fr = l & 15, fg = l >> 4;
    const size_t base = (size_t)bh << 16;
    const int b = bh >> 4, h = bh & 15;

    const int skb = (((l & 7) * 16) ^ ((l >> 3) << 4)) >> 1;
    const int srow = l >> 3;

    bf16x8 qfA[2], qfB[2];
    #pragma unroll
    for (int kk = 0; kk < 2; kk++) {
        qfA[kk] = *(const bf16x8*)(Q + base + (size_t)(qtA * 64 + w * 16 + fr) * 64 + kk * 32 + fg * 8);
        qfB[kk] = *(const bf16x8*)(Q + base + (size_t)(qtB * 64 + w * 16 + fr) * 64 + kk * 32 + fg * 8);
    }

    f32x4 oA[4] = {}, oB[4] = {};
    float mA[4], lsA[4] = {0.f, 0.f, 0.f, 0.f};
    float mB[4], lsB[4] = {0.f, 0.f, 0.f, 0.f};
    #pragma unroll
    for (int rr = 0; rr < 4; rr++) { mA[rr] = -30000.0f; mB[rr] = -30000.0f; }

    auto stage = [&](int buf, int kv0) {
        #pragma unroll
        for (int ci = 0; ci < 2; ++ci) {
            int c = w + ci * 4;
            int row = c * 8 + srow;
            GLD_LDS16(K  + base + (size_t)(kv0 + row) * 64 + skb, sK[buf] + c * 1024);
            GLD_LDS16(Vt + base + (size_t)row * 1024 + kv0 + skb, sV[buf] + c * 1024);
        }
    };

    auto tile_step = [&](int buf, int kv0, int qt, bool diag,
                         bf16x8 (&qf)[2], f32x4 (&o)[4], float (&m)[4], float (&ls)[4]) {
        f32x4 s[4] = {};
        #pragma unroll
        for (int kk = 0; kk < 2; kk++)
            #pragma unroll
            for (int ni = 0; ni < 4; ni++) {
                int off = (ni * 16 + fr) * 128 + ((kk * 64 + fg * 16) ^ ((fr & 7) << 4));
                bf16x8 kf = *(const bf16x8*)(sK[buf] + off);
                s[ni] = __builtin_amdgcn_mfma_f32_16x16x32_bf16(qf[kk], kf, s[ni], 0, 0, 0);
            }
        if (diag) {
            int q0w = qt * 64 + w * 16;
            #pragma unroll
            for (int ni = 0; ni < 4; ni++) {
                int kj = kv0 + ni * 16 + fr;
                #pragma unroll
                for (int rr = 0; rr < 4; rr++) {
                    int qi = q0w + fg * 4 + rr;
                    if (kj > qi) s[ni][rr] = -30000.0f;
                }
            }
        }
        float alpha[4];
        #pragma unroll
        for (int rr = 0; rr < 4; rr++) {
            float mx = fmaxf(fmaxf(s[0][rr], s[1][rr]), fmaxf(s[2][rr], s[3][rr]));
            mx = fmaxf(mx, __shfl_xor(mx, 1));
            mx = fmaxf(mx, __shfl_xor(mx, 2));
            mx = fmaxf(mx, __shfl_xor(mx, 4));
            mx = fmaxf(mx, __shfl_xor(mx, 8));
            float mn = fmaxf(m[rr], mx);
            alpha[rr] = __expf(m[rr] - mn);
            m[rr] = mn;
        }
        float psum[4] = {0.f, 0.f, 0.f, 0.f};
        #pragma unroll
        for (int ni = 0; ni < 4; ni++)
            #pragma unroll
            for (int rr = 0; rr < 4; rr++) {
                float pv = __expf(s[ni][rr] - m[rr]);
                s[ni][rr] = pv;
                psum[rr] += pv;
            }
        #pragma unroll
        for (int rr = 0; rr < 4; rr++) ls[rr] = ls[rr] * alpha[rr] + psum[rr];
        #pragma unroll
        for (int ni = 0; ni < 4; ni++)
            #pragma unroll
            for (int rr = 0; rr < 4; rr++) o[ni][rr] *= alpha[rr];
        // P -> sP (swizzled write; ~2-way max)
        #pragma unroll
        for (int ni = 0; ni < 4; ni++)
            #pragma unroll
            for (int rr = 0; rr < 4; rr++) {
                int prow = fg * 4 + rr, col = ni * 16 + fr;
                *(u16*)(sP[w] + prow * 128 + ((col * 2) ^ ((prow & 7) << 4))) = f2b(s[ni][rr]);
            }
        // O += P @ V  (conflict-free swizzled reads)
        #pragma unroll
        for (int kk = 0; kk < 2; kk++) {
            int poff = fr * 128 + ((kk * 64 + fg * 16) ^ ((fr & 7) << 4));
            bf16x8 pa = *(const bf16x8*)(sP[w] + poff);
            #pragma unroll
            for (int ni = 0; ni < 4; ni++) {
                int voff = (ni * 16 + fr) * 128 + ((kk * 64 + fg * 16) ^ ((fr & 7) << 4));
                bf16x8 vf = *(const bf16x8*)(sV[buf] + voff);
                o[ni] = __builtin_amdgcn_mfma_f32_16x16x32_bf16(pa, vf, o[ni], 0, 0, 0);
            }
        }
    };

    stage(0, 0);
    asm volatile("s_waitcnt vmcnt(0)" ::: "memory");
    __syncthreads();
    int cur = 0;
    for (int kt = 0; kt <= qtB; ++kt) {
        if (kt < qtB) stage(cur ^ 1, (kt + 1) * 64);   // prefetch next tile
        if (kt <= qtA) tile_step(cur, kt * 64, qtA, kt == qtA, qfA, oA, mA, lsA);
        tile_step(cur, kt * 64, qtB, kt == qtB, qfB, oB, mB, lsB);
        asm volatile("s_waitcnt vmcnt(0)" ::: "memory");
        __syncthreads();
        cur ^= 1;
    }

    #pragma unroll
    for (int rr = 0; rr < 4; rr++) {
        float tA = lsA[rr], tB = lsB[rr];
        #pragma unroll
        for (int sft = 1; sft < 16; sft <<= 1) {
            tA += __shfl_xor(tA, sft);
            tB += __shfl_xor(tB, sft);
        }
        lsA[rr] = 1.0f / tA;
        lsB[rr] = 1.0f / tB;
    }
    #pragma unroll
    for (int ni = 0; ni < 4; ni++)
        #pragma unroll
        for (int rr = 0; rr < 4; rr++) {
            int qiA = qtA * 64 + w * 16 + fg * 4 + rr;
            int qiB = qtB * 64 + w * 16 + fg * 4 + rr;
            int d = h * 64 + ni * 16 + fr;
            Y[((size_t)(b * 1024 + qiA)) * 1024 + d] = f2b(oA[ni][rr] * lsA[rr]);
            Y[((size_t)(b * 1024 + qiB)) * 1024 + d] = f2b(oB[ni][rr] * lsB[rr]);
        }
}

// ---------------------------------------------------------------------------
extern "C" void kernel_launch(void* const* d_in, const int* in_sizes, int n_in,
                              void* d_out, int out_size, void* d_ws, size_t ws_size,
                              hipStream_t stream) {
    const float* x    = (const float*)d_in[0];
    const float* Wqd  = (const float*)d_in[1];
    const float* Wkd  = (const float*)d_in[2];
    const float* Wvd  = (const float*)d_in[3];
    const float* Wqc  = (const float*)d_in[4];
    const float* Wqe  = (const float*)d_in[5];
    const float* Wkc  = (const float*)d_in[6];
    const float* Wke  = (const float*)d_in[7];
    const float* Wvu  = (const float*)d_in[8];
    const float* Wc   = (const float*)d_in[9];

    float* dout     = (float*)d_out;          // f32 outputs
    float* y_out    = dout;                   // [4,1024,1024]
    float* klat_out = dout + 4194304;         // [4,1024,16,64]
    float* vlat_out = dout + 8388608;         // [4,1024,16,64]

    const size_t MiB = 1024 * 1024;
    // d_out y-region (16 MiB, written last) doubles as scratch:
    //   phase A: xb @ +0 (8M), WqdT @ +8M, WkdT @ +10M, WvdT @ +12M
    //   phase B: Qw @ +0 (8M), Kw @ +8M (8M)
    char* db = (char*)d_out;
    u16* xb   = (u16*)db;
    u16* WqdT = (u16*)(db + 8  * MiB);
    u16* WkdT = (u16*)(db + 10 * MiB);
    u16* WvdT = (u16*)(db + 12 * MiB);
    u16* Qw   = (u16*)db;
    u16* Kw   = (u16*)(db + 8 * MiB);

    // d_ws: 18 MiB total (R5 proved ws_size >= 24 MiB)
    char* ws = (char*)d_ws;
    u16* WcT  = (u16*)ws;                     // 2 MiB  [-> final gemm]
    u16* qlat = (u16*)(ws + 2 * MiB);         // 8 MiB  [gemm -> upproj]
    u16* Ya   = (u16*)(ws + 2 * MiB);         // overlay [attn -> final gemm]
    u16* Vtw  = (u16*)(ws + 10 * MiB);        // 8 MiB  [upproj -> attn], [b][h][d][t]

    convert_x<<<dim3(2048), 256, 0, stream>>>(x, xb);
    transpose4<<<dim3(16, 16, 4), 256, 0, stream>>>(Wqd, Wkd, Wvd, Wc,
                                                    WqdT, WkdT, WvdT, WcT);
    gemm128_down<<<dim3(32, 8, 3), 256, 0, stream>>>(xb, WqdT, WkdT, WvdT,
                                                     qlat, klat_out, vlat_out);
    upproj_mfma<<<dim3(64, 16), 192, 0, stream>>>(qlat, klat_out, vlat_out,
                                                  Wqc, Wqe, Wkc, Wke, Wvu,
                                                  Qw, Kw, Vtw);
    attn<<<dim3(64, 8), 256, 0, stream>>>(Qw, Kw, Vtw, Ya);
    gemm128_out<<<dim3(32, 8), 256, 0, stream>>>(Ya, WcT, y_out);
}

// Round 9
// 100.646 us; speedup vs baseline: 3.0209x; 1.2602x over previous
//
#include <hip/hip_runtime.h>

typedef unsigned short u16;
typedef unsigned int   u32;
typedef __bf16 bf16x8 __attribute__((ext_vector_type(8)));
typedef float  f32x4  __attribute__((ext_vector_type(4)));

// Contract (established R0-R8): inputs f32, outputs f32.
// d_out = y[4M f32] | k_lat[4M f32] | v_lat[4M f32]. ws_size = 256 MiB
// (harness poison fill of exactly 262144 KB observed in R8 counters).

__device__ __forceinline__ float b2f(u16 u) {
    u32 x = ((u32)u) << 16; float f; __builtin_memcpy(&f, &x, 4); return f;
}
__device__ __forceinline__ u16 f2b(float f) {
    u32 x; __builtin_memcpy(&x, &f, 4);
    u32 r = x + 0x7FFFu + ((x >> 16) & 1u);
    return (u16)(r >> 16);
}

#define GLD_LDS16(src, dst) \
  __builtin_amdgcn_global_load_lds((const __attribute__((address_space(1))) unsigned int*)(src), \
                                   (__attribute__((address_space(3))) unsigned int*)(dst), 16, 0, 0)

// ---------------------------------------------------------------------------
// prep: merged weight-transpose (blocks 0..1023) + x f32->bf16 (1024..3071)
// ---------------------------------------------------------------------------
__global__ __launch_bounds__(256) void prep(
    const float* __restrict__ x, u16* __restrict__ xb,
    const float* __restrict__ W0, const float* __restrict__ W1,
    const float* __restrict__ W2, const float* __restrict__ W3,
    u16* __restrict__ T0, u16* __restrict__ T1,
    u16* __restrict__ T2, u16* __restrict__ T3)
{
    const int bx = blockIdx.x, tid = threadIdx.x;
    if (bx >= 1024) {
        int i0 = ((bx - 1024) * 256 + tid) * 8;
        #pragma unroll
        for (int j = 0; j < 8; j++) xb[i0 + j] = f2b(x[i0 + j]);
        return;
    }
    __shared__ u16 t[64][65];
    int z = bx >> 8, xy = bx & 255;
    const float* W = (z == 0) ? W0 : (z == 1) ? W1 : (z == 2) ? W2 : W3;
    u16* O = (z == 0) ? T0 : (z == 1) ? T1 : (z == 2) ? T2 : T3;
    int r0 = (xy >> 4) * 64, c0 = (xy & 15) * 64;
    int row = tid >> 2, seg = (tid & 3) * 16;
    #pragma unroll
    for (int i = 0; i < 16; i++)
        t[row][seg + i] = f2b(W[(size_t)(r0 + row) * 1024 + c0 + seg + i]);
    __syncthreads();
    #pragma unroll
    for (int i = 0; i < 16; i++)
        O[(size_t)(c0 + row) * 1024 + r0 + seg + i] = t[seg + i][row];
}

// ---------------------------------------------------------------------------
// Fused down-projection GEMM + up-projection + RoPE.
// grid (32, 8, 3). z: 0=Q-path, 1=K-path, 2=V-path.
// Main loop: 128x128 down-proj tile (m97 recipe). Epilogue: each wave's
// 64x64 sub-tile = one head's latent panel -> LDS -> 16-MFMA up-proj vs
// LDS-staged up-weights -> RoPE (z<2) / transposed-V (z=2) stores.
// z=1/2 additionally store the latent f32 to d_out (k_lat / v_lat).
// ---------------------------------------------------------------------------
__global__ __launch_bounds__(256) void gemm_fused(
    const u16* __restrict__ A,
    const u16* __restrict__ Bt0, const u16* __restrict__ Bt1, const u16* __restrict__ Bt2,
    const float* __restrict__ Wqc, const float* __restrict__ Wqe,
    const float* __restrict__ Wkc, const float* __restrict__ Wke,
    const float* __restrict__ Wv,
    float* __restrict__ klat_out, float* __restrict__ vlat_out,
    u16* __restrict__ Qo, u16* __restrict__ Ko, u16* __restrict__ Vto)
{
    constexpr int K = 1024, N = 1024;
    __shared__ __align__(16) char smem[40960];   // sA 16K | sB 16K | sW 8K
    char* sA = smem;
    char* sB = smem + 16384;
    u16 (*sW)[64][8] = (u16(*)[64][8])(smem + 32768);
    const int tid = threadIdx.x;
    const int w = tid >> 6, l = tid & 63;
    const int z = blockIdx.z;
    const u16* Bt = (z == 0) ? Bt0 : (z == 1) ? Bt1 : Bt2;
    const int m0 = blockIdx.x * 128, n0 = blockIdx.y * 128;
    const int wr = w >> 1, wc = w & 1;
    const int fr = l & 15, fg = l >> 4;

    // stage up-weights k-chunk-major: sW[k>>3][n][k&7]
    for (int e = tid; e < 4096; e += 256) {
        int k = e >> 6, n = e & 63;
        float v;
        if (z == 2)      v = Wv[k * 64 + n];
        else if (z == 0) v = (n < 32) ? Wqc[k * 32 + n] : Wqe[k * 32 + n - 32];
        else             v = (n < 32) ? Wkc[k * 32 + n] : Wke[k * 32 + n - 32];
        sW[k >> 3][n][k & 7] = f2b(v);
    }

    const int skb = (((l & 7) * 16) ^ ((l >> 3) << 4)) >> 1;
    const int srow = l >> 3;
    f32x4 acc[4][4] = {};

    for (int kt = 0; kt < 16; ++kt) {
        const int k0 = kt * 64;
        if (kt > 0) __syncthreads();
        #pragma unroll
        for (int ci = 0; ci < 4; ++ci) {
            int c = w + ci * 4;
            int row = c * 8 + srow;
            GLD_LDS16(A  + (size_t)(m0 + row) * K + k0 + skb, sA + c * 1024);
            GLD_LDS16(Bt + (size_t)(n0 + row) * K + k0 + skb, sB + c * 1024);
        }
        asm volatile("s_waitcnt vmcnt(0)" ::: "memory");
        __syncthreads();
        #pragma unroll
        for (int kk = 0; kk < 2; ++kk) {
            bf16x8 af[4], bf[4];
            #pragma unroll
            for (int mi = 0; mi < 4; ++mi) {
                int row = wr * 64 + mi * 16 + fr;
                int off = row * 128 + ((kk * 64 + fg * 16) ^ ((fr & 7) << 4));
                af[mi] = *(const bf16x8*)(sA + off);
            }
            #pragma unroll
            for (int ni = 0; ni < 4; ++ni) {
                int row = wc * 64 + ni * 16 + fr;
                int off = row * 128 + ((kk * 64 + fg * 16) ^ ((fr & 7) << 4));
                bf[ni] = *(const bf16x8*)(sB + off);
            }
            #pragma unroll
            for (int mi = 0; mi < 4; ++mi)
                #pragma unroll
                for (int ni = 0; ni < 4; ++ni)
                    acc[mi][ni] = __builtin_amdgcn_mfma_f32_16x16x32_bf16(af[mi], bf[ni], acc[mi][ni], 0, 0, 0);
        }
    }

    // latent f32 output for K/V paths
    if (z) {
        float* L = (z == 1) ? klat_out : vlat_out;
        #pragma unroll
        for (int mi = 0; mi < 4; ++mi)
            #pragma unroll
            for (int ni = 0; ni < 4; ++ni)
                #pragma unroll
                for (int rr = 0; rr < 4; ++rr) {
                    int r = m0 + wr * 64 + mi * 16 + fg * 4 + rr;
                    int c = n0 + wc * 64 + ni * 16 + fr;
                    L[(size_t)r * N + c] = acc[mi][ni][rr];
                }
    }

    __syncthreads();   // all sA/sB MFMA reads done -> safe to overwrite with sL

    // latent panel -> LDS (per-wave 64x64 u16, row-major, XOR-swizzled)
    char* sL = smem + w * 8192;
    #pragma unroll
    for (int mi = 0; mi < 4; ++mi)
        #pragma unroll
        for (int ni = 0; ni < 4; ++ni)
            #pragma unroll
            for (int rr = 0; rr < 4; ++rr) {
                int row = mi * 16 + fg * 4 + rr;
                int lat = ni * 16 + fr;
                int byte = row * 128 + ((((lat >> 3) ^ (row & 7)) << 4) | ((lat & 7) << 1));
                *(u16*)(sL + byte) = f2b(acc[mi][ni][rr]);
            }
    __syncthreads();

    // up-proj: [64 rows x 64 lat] @ [64 lat x 64 d]
    bf16x8 af2[4][2], bf2[4][2];
    #pragma unroll
    for (int mi = 0; mi < 4; ++mi)
        #pragma unroll
        for (int kk = 0; kk < 2; ++kk) {
            int row = mi * 16 + fr;
            af2[mi][kk] = *(const bf16x8*)(sL + row * 128 + (((kk * 4 + fg) ^ (row & 7)) << 4));
        }
    #pragma unroll
    for (int ni = 0; ni < 4; ++ni)
        #pragma unroll
        for (int kk = 0; kk < 2; ++kk)
            bf2[ni][kk] = *(const bf16x8*)&sW[kk * 4 + fg][ni * 16 + fr][0];

    f32x4 o2[4][4] = {};
    #pragma unroll
    for (int kk = 0; kk < 2; ++kk)
        #pragma unroll
        for (int mi = 0; mi < 4; ++mi)
            #pragma unroll
            for (int ni = 0; ni < 4; ++ni)
                o2[mi][ni] = __builtin_amdgcn_mfma_f32_16x16x32_bf16(af2[mi][kk], bf2[ni][kk], o2[mi][ni], 0, 0, 0);

    const int rbase = m0 + wr * 64;
    const int b = rbase >> 10, tbase = rbase & 1023;
    const int h = blockIdx.y * 2 + wc;
    const size_t obase = ((size_t)(b * 16 + h)) << 16;

    if (z == 2) {
        // V: write transposed Vt[d][t]; rr are consecutive t -> 8B stores
        #pragma unroll
        for (int mi = 0; mi < 4; ++mi)
            #pragma unroll
            for (int ni = 0; ni < 4; ++ni) {
                union { u16 u[4]; uint2 v; } pk;
                #pragma unroll
                for (int rr = 0; rr < 4; ++rr) pk.u[rr] = f2b(o2[mi][ni][rr]);
                int t0 = tbase + mi * 16 + fg * 4;
                int d = ni * 16 + fr;
                *(uint2*)(Vto + obase + (size_t)d * 1024 + t0) = pk.v;
            }
    } else {
        const float qscale = (z == 0) ? 0.125f : 1.0f;
        const float rf = __expf(-(float)fr * 0.5756462732485115f);  // ln(1e4)/16
        u16* O = (z == 0) ? Qo : Ko;
        #pragma unroll
        for (int mi = 0; mi < 4; ++mi) {
            #pragma unroll
            for (int rr = 0; rr < 4; ++rr) {
                int t = tbase + mi * 16 + fg * 4 + rr;
                float ang = (float)t * rf;
                float sn = __sinf(ang), cs = __cosf(ang);
                #pragma unroll
                for (int ni = 0; ni < 4; ++ni) {
                    float a = o2[mi][ni][rr];
                    float p = __shfl_xor(a, 1);
                    if (ni >= 2)
                        a = a * cs + ((fr & 1) ? p : -p) * sn;
                    a *= qscale;
                    O[obase + (size_t)t * 64 + ni * 16 + fr] = f2b(a);
                }
            }
        }
    }
}

// ---------------------------------------------------------------------------
// Out-projection GEMM (m97 recipe): y = Ya @ WcT^T, f32 out.
// ---------------------------------------------------------------------------
__global__ __launch_bounds__(256) void gemm128_out(
    const u16* __restrict__ A, const u16* __restrict__ Bt, float* __restrict__ Cf)
{
    constexpr int K = 1024, N = 1024;
    __shared__ __align__(16) char sA[16384];
    __shared__ __align__(16) char sB[16384];
    const int tid = threadIdx.x;
    const int w = tid >> 6, l = tid & 63;
    const int m0 = blockIdx.x * 128, n0 = blockIdx.y * 128;
    const int wr = w >> 1, wc = w & 1;
    const int fr = l & 15, fg = l >> 4;
    const int skb = (((l & 7) * 16) ^ ((l >> 3) << 4)) >> 1;
    const int srow = l >> 3;
    f32x4 acc[4][4] = {};
    for (int kt = 0; kt < 16; ++kt) {
        const int k0 = kt * 64;
        if (kt > 0) __syncthreads();
        #pragma unroll
        for (int ci = 0; ci < 4; ++ci) {
            int c = w + ci * 4;
            int row = c * 8 + srow;
            GLD_LDS16(A  + (size_t)(m0 + row) * K + k0 + skb, sA + c * 1024);
            GLD_LDS16(Bt + (size_t)(n0 + row) * K + k0 + skb, sB + c * 1024);
        }
        asm volatile("s_waitcnt vmcnt(0)" ::: "memory");
        __syncthreads();
        #pragma unroll
        for (int kk = 0; kk < 2; ++kk) {
            bf16x8 af[4], bf[4];
            #pragma unroll
            for (int mi = 0; mi < 4; ++mi) {
                int row = wr * 64 + mi * 16 + fr;
                int off = row * 128 + ((kk * 64 + fg * 16) ^ ((fr & 7) << 4));
                af[mi] = *(const bf16x8*)(sA + off);
            }
            #pragma unroll
            for (int ni = 0; ni < 4; ++ni) {
                int row = wc * 64 + ni * 16 + fr;
                int off = row * 128 + ((kk * 64 + fg * 16) ^ ((fr & 7) << 4));
                bf[ni] = *(const bf16x8*)(sB + off);
            }
            #pragma unroll
            for (int mi = 0; mi < 4; ++mi)
                #pragma unroll
                for (int ni = 0; ni < 4; ++ni)
                    acc[mi][ni] = __builtin_amdgcn_mfma_f32_16x16x32_bf16(af[mi], bf[ni], acc[mi][ni], 0, 0, 0);
        }
    }
    #pragma unroll
    for (int mi = 0; mi < 4; ++mi)
        #pragma unroll
        for (int ni = 0; ni < 4; ++ni)
            #pragma unroll
            for (int rr = 0; rr < 4; ++rr) {
                int r = m0 + wr * 64 + mi * 16 + fg * 4 + rr;
                int c = n0 + wc * 64 + ni * 16 + fr;
                Cf[(size_t)r * N + c] = acc[mi][ni][rr];
            }
}

// ---------------------------------------------------------------------------
// Flash-style causal MFMA attention (R8 structure, unchanged):
// grid (bh=64, p=8); Q-tiles qtA=p, qtB=15-p; swizzled global_load_lds K/Vt,
// double-buffered; swizzled sP.
// ---------------------------------------------------------------------------
__global__ __launch_bounds__(256) void attn(
    const u16* __restrict__ Q, const u16* __restrict__ K,
    const u16* __restrict__ Vt, u16* __restrict__ Y)
{
    __shared__ __align__(16) char sK[2][8192];
    __shared__ __align__(16) char sV[2][8192];
    __shared__ __align__(16) char sP[4][2048];
    const int tid = threadIdx.x, w = tid >> 6, l = tid & 63;
    const int bh = blockIdx.x, p = blockIdx.y;
    const int qtA = p, qtB = 15 - p;
    const int fr = l & 15, fg = l >> 4;
    const size_t base = (size_t)bh << 16;
    const int b = bh >> 4, h = bh & 15;

    const int skb = (((l & 7) * 16) ^ ((l >> 3) << 4)) >> 1;
    const int srow = l >> 3;

    bf16x8 qfA[2], qfB[2];
    #pragma unroll
    for (int kk = 0; kk < 2; kk++) {
        qfA[kk] = *(const bf16x8*)(Q + base + (size_t)(qtA * 64 + w * 16 + fr) * 64 + kk * 32 + fg * 8);
        qfB[kk] = *(const bf16x8*)(Q + base + (size_t)(qtB * 64 + w * 16 + fr) * 64 + kk * 32 + fg * 8);
    }

    f32x4 oA[4] = {}, oB[4] = {};
    float mA[4], lsA[4] = {0.f, 0.f, 0.f, 0.f};
    float mB[4], lsB[4] = {0.f, 0.f, 0.f, 0.f};
    #pragma unroll
    for (int rr = 0; rr < 4; rr++) { mA[rr] = -30000.0f; mB[rr] = -30000.0f; }

    auto stage = [&](int buf, int kv0) {
        #pragma unroll
        for (int ci = 0; ci < 2; ++ci) {
            int c = w + ci * 4;
            int row = c * 8 + srow;
            GLD_LDS16(K  + base + (size_t)(kv0 + row) * 64 + skb, sK[buf] + c * 1024);
            GLD_LDS16(Vt + base + (size_t)row * 1024 + kv0 + skb, sV[buf] + c * 1024);
        }
    };

    auto tile_step = [&](int buf, int kv0, int qt, bool diag,
                         bf16x8 (&qf)[2], f32x4 (&o)[4], float (&m)[4], float (&ls)[4]) {
        f32x4 s[4] = {};
        #pragma unroll
        for (int kk = 0; kk < 2; kk++)
            #pragma unroll
            for (int ni = 0; ni < 4; ni++) {
                int off = (ni * 16 + fr) * 128 + ((kk * 64 + fg * 16) ^ ((fr & 7) << 4));
                bf16x8 kf = *(const bf16x8*)(sK[buf] + off);
                s[ni] = __builtin_amdgcn_mfma_f32_16x16x32_bf16(qf[kk], kf, s[ni], 0, 0, 0);
            }
        if (diag) {
            int q0w = qt * 64 + w * 16;
            #pragma unroll
            for (int ni = 0; ni < 4; ni++) {
                int kj = kv0 + ni * 16 + fr;
                #pragma unroll
                for (int rr = 0; rr < 4; rr++) {
                    int qi = q0w + fg * 4 + rr;
                    if (kj > qi) s[ni][rr] = -30000.0f;
                }
            }
        }
        float alpha[4];
        #pragma unroll
        for (int rr = 0; rr < 4; rr++) {
            float mx = fmaxf(fmaxf(s[0][rr], s[1][rr]), fmaxf(s[2][rr], s[3][rr]));
            mx = fmaxf(mx, __shfl_xor(mx, 1));
            mx = fmaxf(mx, __shfl_xor(mx, 2));
            mx = fmaxf(mx, __shfl_xor(mx, 4));
            mx = fmaxf(mx, __shfl_xor(mx, 8));
            float mn = fmaxf(m[rr], mx);
            alpha[rr] = __expf(m[rr] - mn);
            m[rr] = mn;
        }
        float psum[4] = {0.f, 0.f, 0.f, 0.f};
        #pragma unroll
        for (int ni = 0; ni < 4; ni++)
            #pragma unroll
            for (int rr = 0; rr < 4; rr++) {
                float pv = __expf(s[ni][rr] - m[rr]);
                s[ni][rr] = pv;
                psum[rr] += pv;
            }
        #pragma unroll
        for (int rr = 0; rr < 4; rr++) ls[rr] = ls[rr] * alpha[rr] + psum[rr];
        #pragma unroll
        for (int ni = 0; ni < 4; ni++)
            #pragma unroll
            for (int rr = 0; rr < 4; rr++) o[ni][rr] *= alpha[rr];
        #pragma unroll
        for (int ni = 0; ni < 4; ni++)
            #pragma unroll
            for (int rr = 0; rr < 4; rr++) {
                int prow = fg * 4 + rr, col = ni * 16 + fr;
                *(u16*)(sP[w] + prow * 128 + ((col * 2) ^ ((prow & 7) << 4))) = f2b(s[ni][rr]);
            }
        #pragma unroll
        for (int kk = 0; kk < 2; kk++) {
            int poff = fr * 128 + ((kk * 64 + fg * 16) ^ ((fr & 7) << 4));
            bf16x8 pa = *(const bf16x8*)(sP[w] + poff);
            #pragma unroll
            for (int ni = 0; ni < 4; ni++) {
                int voff = (ni * 16 + fr) * 128 + ((kk * 64 + fg * 16) ^ ((fr & 7) << 4));
                bf16x8 vf = *(const bf16x8*)(sV[buf] + voff);
                o[ni] = __builtin_amdgcn_mfma_f32_16x16x32_bf16(pa, vf, o[ni], 0, 0, 0);
            }
        }
    };

    stage(0, 0);
    asm volatile("s_waitcnt vmcnt(0)" ::: "memory");
    __syncthreads();
    int cur = 0;
    for (int kt = 0; kt <= qtB; ++kt) {
        if (kt < qtB) stage(cur ^ 1, (kt + 1) * 64);
        if (kt <= qtA) tile_step(cur, kt * 64, qtA, kt == qtA, qfA, oA, mA, lsA);
        tile_step(cur, kt * 64, qtB, kt == qtB, qfB, oB, mB, lsB);
        asm volatile("s_waitcnt vmcnt(0)" ::: "memory");
        __syncthreads();
        cur ^= 1;
    }

    #pragma unroll
    for (int rr = 0; rr < 4; rr++) {
        float tA = lsA[rr], tB = lsB[rr];
        #pragma unroll
        for (int sft = 1; sft < 16; sft <<= 1) {
            tA += __shfl_xor(tA, sft);
            tB += __shfl_xor(tB, sft);
        }
        lsA[rr] = 1.0f / tA;
        lsB[rr] = 1.0f / tB;
    }
    #pragma unroll
    for (int ni = 0; ni < 4; ni++)
        #pragma unroll
        for (int rr = 0; rr < 4; rr++) {
            int qiA = qtA * 64 + w * 16 + fg * 4 + rr;
            int qiB = qtB * 64 + w * 16 + fg * 4 + rr;
            int d = h * 64 + ni * 16 + fr;
            Y[((size_t)(b * 1024 + qiA)) * 1024 + d] = f2b(oA[ni][rr] * lsA[rr]);
            Y[((size_t)(b * 1024 + qiB)) * 1024 + d] = f2b(oB[ni][rr] * lsB[rr]);
        }
}

// ---------------------------------------------------------------------------
extern "C" void kernel_launch(void* const* d_in, const int* in_sizes, int n_in,
                              void* d_out, int out_size, void* d_ws, size_t ws_size,
                              hipStream_t stream) {
    const float* x    = (const float*)d_in[0];
    const float* Wqd  = (const float*)d_in[1];
    const float* Wkd  = (const float*)d_in[2];
    const float* Wvd  = (const float*)d_in[3];
    const float* Wqc  = (const float*)d_in[4];
    const float* Wqe  = (const float*)d_in[5];
    const float* Wkc  = (const float*)d_in[6];
    const float* Wke  = (const float*)d_in[7];
    const float* Wvu  = (const float*)d_in[8];
    const float* Wc   = (const float*)d_in[9];

    float* dout     = (float*)d_out;
    float* y_out    = dout;                   // [4,1024,1024]
    float* klat_out = dout + 4194304;         // [4,1024,16,64]
    float* vlat_out = dout + 8388608;         // [4,1024,16,64]

    const size_t MiB = 1024 * 1024;
    char* ws = (char*)d_ws;                   // 256 MiB; we use 48 MiB
    u16* WqdT = (u16*)(ws);
    u16* WkdT = (u16*)(ws + 2  * MiB);
    u16* WvdT = (u16*)(ws + 4  * MiB);
    u16* WcT  = (u16*)(ws + 6  * MiB);
    u16* xb   = (u16*)(ws + 8  * MiB);        // [4096][1024] bf16
    u16* Qw   = (u16*)(ws + 16 * MiB);        // [B][H][T][64]
    u16* Kw   = (u16*)(ws + 24 * MiB);
    u16* Vtw  = (u16*)(ws + 32 * MiB);        // [B][H][64][T]
    u16* Ya   = (u16*)(ws + 40 * MiB);        // [4096][1024] bf16

    prep<<<dim3(3072), 256, 0, stream>>>(x, xb, Wqd, Wkd, Wvd, Wc,
                                         WqdT, WkdT, WvdT, WcT);
    gemm_fused<<<dim3(32, 8, 3), 256, 0, stream>>>(xb, WqdT, WkdT, WvdT,
                                                   Wqc, Wqe, Wkc, Wke, Wvu,
                                                   klat_out, vlat_out,
                                                   Qw, Kw, Vtw);
    attn<<<dim3(64, 8), 256, 0, stream>>>(Qw, Kw, Vtw, Ya);
    gemm128_out<<<dim3(32, 8), 256, 0, stream>>>(Ya, WcT, y_out);
}